// Round 1
// baseline (95.752 us; speedup 1.0000x reference)
//
#include <hip/hip_runtime.h>

// CRF NLL forward, B=8192, L=512, T=6 (4 real states + START/STOP).
// One lane per batch. Scaled-probability domain: alpha_i = mex*ln2 + log(q_i).
// Per step: q <- diag(exp(feat)) * E * q, renormalized by 2^-e (exponent of max).
// Gold path score fused (tags LUT via LDS, emission from in-register feats).

#define LN2F 0.69314718055994530942f

// Load one chunk of 4 timesteps: 24 floats (6x float4, 16B-aligned since
// chunk base = l0*24B, l0 % 4 == 0) + 4 tags (int4).
#define LOADC(P0,P1,P2,P3,P4,P5,PT,K)                                   \
  do {                                                                  \
    const int l0_ = (K) * 4;                                            \
    if (l0_ < 512) {                                                    \
      const float4* p_ = (const float4*)(fb + l0_ * 6);                 \
      P0 = p_[0]; P1 = p_[1]; P2 = p_[2];                               \
      P3 = p_[3]; P4 = p_[4]; P5 = p_[5];                               \
      PT = *(const int4*)(tb + l0_);                                    \
    }                                                                   \
  } while (0)

// One recurrence step + gold accumulation, fully predicated on l < len.
#define STEP(FA,FB,FC,FD,TGV,LUTV,L)                                    \
  do {                                                                  \
    const bool act_   = (L) < len;                                      \
    const bool first_ = (L) == 0;                                       \
    const float fa_=(FA), fb2_=(FB), fc_=(FC), fd_=(FD);                \
    const float fe0_=__expf(fa_), fe1_=__expf(fb2_);                    \
    const float fe2_=__expf(fc_), fe3_=__expf(fd_);                     \
    float s0_ = fmaf(E00,q0, fmaf(E01,q1, fmaf(E02,q2, E03*q3)));       \
    float s1_ = fmaf(E10,q0, fmaf(E11,q1, fmaf(E12,q2, E13*q3)));       \
    float s2_ = fmaf(E20,q0, fmaf(E21,q1, fmaf(E22,q2, E23*q3)));       \
    float s3_ = fmaf(E30,q0, fmaf(E31,q1, fmaf(E32,q2, E33*q3)));       \
    s0_ = first_ ? e40 : s0_;  s1_ = first_ ? e41 : s1_;                \
    s2_ = first_ ? e42 : s2_;  s3_ = first_ ? e43 : s3_;                \
    const float t0_ = s0_*fe0_, t1_ = s1_*fe1_;                         \
    const float t2_ = s2_*fe2_, t3_ = s3_*fe3_;                         \
    const float cm_ = fmaxf(fmaxf(t0_,t1_), fmaxf(t2_,t3_));            \
    const int ee_ = (int)(__float_as_uint(cm_) >> 23) - 127;            \
    const float n0_ = ldexpf(t0_,-ee_), n1_ = ldexpf(t1_,-ee_);         \
    const float n2_ = ldexpf(t2_,-ee_), n3_ = ldexpf(t3_,-ee_);         \
    q0 = act_ ? n0_ : q0;  q1 = act_ ? n1_ : q1;                        \
    q2 = act_ ? n2_ : q2;  q3 = act_ ? n3_ : q3;                        \
    mex = act_ ? (mex + ee_) : mex;                                     \
    const int tg_ = (TGV);                                              \
    const float fs_ = (tg_ & 2) ? ((tg_ & 1) ? fd_ : fc_)               \
                                : ((tg_ & 1) ? fb2_ : fa_);             \
    gold += act_ ? ((LUTV) + fs_) : 0.0f;                               \
    prev = act_ ? tg_ : prev;                                           \
  } while (0)

// Process one 4-step chunk. Transition-LUT LDS reads are issued up front
// (indices depend only on tags), so ds_read latency hides under the FMAs.
#define PROC(P0,P1,P2,P3,P4,P5,PT,K)                                    \
  do {                                                                  \
    const int l0p_ = (K) * 4;                                           \
    const int g0_ = (PT).x & 3, g1_ = (PT).y & 3;                       \
    const int g2_ = (PT).z & 3, g3_ = (PT).w & 3;                       \
    const float u0_ = sT[g0_*6 + prev];                                 \
    const float u1_ = sT[g1_*6 + g0_];                                  \
    const float u2_ = sT[g2_*6 + g1_];                                  \
    const float u3_ = sT[g3_*6 + g2_];                                  \
    STEP((P0).x,(P0).y,(P0).z,(P0).w, g0_, u0_, l0p_+0);                \
    STEP((P1).z,(P1).w,(P2).x,(P2).y, g1_, u1_, l0p_+1);                \
    STEP((P3).x,(P3).y,(P3).z,(P3).w, g2_, u2_, l0p_+2);                \
    STEP((P4).z,(P4).w,(P5).x,(P5).y, g3_, u3_, l0p_+3);                \
  } while (0)

__global__ __launch_bounds__(64) void crf_fwd_kernel(
    const float* __restrict__ feats,
    const float* __restrict__ trans,
    const int*   __restrict__ tags,
    const int*   __restrict__ lens,
    float* __restrict__ out)
{
    __shared__ float sT[36];   // raw transitions (gold LUT + finals)
    __shared__ float sE[16];   // exp(trans[i][j]) i,j in 0..3
    __shared__ float sE4[4];   // exp(trans[i][START])
    __shared__ float sE5[4];   // exp(trans[STOP][i])

    const int tid = threadIdx.x;
    if (tid < 36) sT[tid] = trans[tid];
    if (tid < 16) sE[tid] = __expf(trans[(tid >> 2) * 6 + (tid & 3)]);
    if (tid < 4) {
        sE4[tid] = __expf(trans[tid * 6 + 4]);
        sE5[tid] = __expf(trans[30 + tid]);
    }
    __syncthreads();

    const int b   = blockIdx.x * 64 + tid;
    const int len = lens[b];
    const float* fb = feats + (size_t)b * 3072;   // 512*6
    const int*   tb = tags  + (size_t)b * 512;

    // Uniform constants into registers (broadcast LDS reads).
    const float E00=sE[0],  E01=sE[1],  E02=sE[2],  E03=sE[3];
    const float E10=sE[4],  E11=sE[5],  E12=sE[6],  E13=sE[7];
    const float E20=sE[8],  E21=sE[9],  E22=sE[10], E23=sE[11];
    const float E30=sE[12], E31=sE[13], E32=sE[14], E33=sE[15];
    const float e40=sE4[0], e41=sE4[1], e42=sE4[2], e43=sE4[3];
    const float e50=sE5[0], e51=sE5[1], e52=sE5[2], e53=sE5[3];

    float q0=0.f, q1=0.f, q2=0.f, q3=0.f;
    int   mex  = 0;
    float gold = 0.f;
    int   prev = 4;   // START

    const float4 z4 = make_float4(0.f,0.f,0.f,0.f);
    const int4   zi = make_int4(0,0,0,0);
    float4 a0=z4,a1=z4,a2=z4,a3=z4,a4=z4,a5=z4;
    float4 b0=z4,b1=z4,b2=z4,b3=z4,b4=z4,b5=z4;
    float4 c0=z4,c1=z4,c2=z4,c3=z4,c4=z4,c5=z4;
    float4 d0=z4,d1=z4,d2=z4,d3=z4,d4=z4,d5=z4;
    int4 at=zi, bt=zi, ct=zi, dt=zi;

    // Prime 3 chunks of prefetch depth.
    LOADC(a0,a1,a2,a3,a4,a5,at, 0);
    LOADC(b0,b1,b2,b3,b4,b5,bt, 1);
    LOADC(c0,c1,c2,c3,c4,c5,ct, 2);

    const int nch = (len + 3) >> 2;
    const int KK  = (nch + 3) & ~3;   // round up; extra chunks fully masked

    for (int k = 0; k < KK; k += 4) {
        LOADC(d0,d1,d2,d3,d4,d5,dt, k+3);  PROC(a0,a1,a2,a3,a4,a5,at, k);
        LOADC(a0,a1,a2,a3,a4,a5,at, k+4);  PROC(b0,b1,b2,b3,b4,b5,bt, k+1);
        LOADC(b0,b1,b2,b3,b4,b5,bt, k+5);  PROC(c0,c1,c2,c3,c4,c5,ct, k+2);
        LOADC(c0,c1,c2,c3,c4,c5,ct, k+6);  PROC(d0,d1,d2,d3,d4,d5,dt, k+3);
    }

    // log Z = mex*ln2 + log( sum_i q_i * exp(trans[STOP][i]) )
    const float dot5 = fmaf(e50,q0, fmaf(e51,q1, fmaf(e52,q2, e53*q3)));
    const float logz = fmaf((float)mex, LN2F, __logf(dot5));
    gold += sT[30 + prev];            // trans[STOP][last_tag], prev in 0..3
    float r = logz - gold;

    // Wave-level sum (block == 1 wave), then one atomic per block.
    #pragma unroll
    for (int off = 32; off > 0; off >>= 1)
        r += __shfl_xor(r, off, 64);
    if (tid == 0)
        atomicAdd(out, r * (1.0f / 8192.0f));
}

extern "C" void kernel_launch(void* const* d_in, const int* in_sizes, int n_in,
                              void* d_out, int out_size, void* d_ws, size_t ws_size,
                              hipStream_t stream) {
    const float* feats = (const float*)d_in[0];
    const float* trans = (const float*)d_in[1];
    const int*   tags  = (const int*)d_in[2];
    const int*   lens  = (const int*)d_in[3];
    float* out = (float*)d_out;

    hipMemsetAsync(out, 0, sizeof(float) * out_size, stream);
    crf_fwd_kernel<<<128, 64, 0, stream>>>(feats, trans, tags, lens, out);
}

// Round 2
// 46.221 us; speedup vs baseline: 2.0716x; 2.0716x over previous
//
#include <hip/hip_runtime.h>

// CRF NLL forward, B=8192, L=512, T=6 (4 real states + START/STOP).
// Two-phase associative scan:
//   Phase 1 (crf_seg<S>): one lane per (batch, segment). Segment 0 computes the
//     4-vector q (scaled-prob domain); segments s>0 compute the 4x4 transfer
//     matrix P = prod_l diag(exp(feat_l)) * E over their active (prefix) steps.
//     Power-of-2 renorm, exponent accumulated in an int. Gold path fused.
//   Phase 2 (crf_comb<S>): per batch, v = P_{S-1} ... P_1 v_0, finalize logZ,
//     subtract gold, wave-reduce, one atomicAdd per block.

#define BB 8192
#define LL 512
#define LN2F 0.69314718055994530942f

// ---- load one 4-step chunk: 24 floats (6x float4) + 4 tags (int4) ----
#define LOADC(B0,B1,B2,B3,B4,B5,TG,C)                                   \
  do { if ((C) < NCH) {                                                 \
    const float4* p_ = (const float4*)(fb + (C)*24);                    \
    B0=p_[0]; B1=p_[1]; B2=p_[2]; B3=p_[3]; B4=p_[4]; B5=p_[5];         \
    TG = *(const int4*)(tb + (C)*4); } } while(0)

// ======================= vector path (segment 0) =======================
#define VSTEP(FA,FB,FC,FD,TGV,LUTV,R)                                   \
  do {                                                                  \
    const bool act_   = (R) < act;                                      \
    const bool first_ = (R) == 0;                                       \
    const float fa_=(FA), fb2_=(FB), fc_=(FC), fd_=(FD);                \
    const float fe0_=__expf(fa_), fe1_=__expf(fb2_);                    \
    const float fe2_=__expf(fc_), fe3_=__expf(fd_);                     \
    float s0_ = fmaf(E[0],q0, fmaf(E[1],q1, fmaf(E[2],q2, E[3]*q3)));   \
    float s1_ = fmaf(E[4],q0, fmaf(E[5],q1, fmaf(E[6],q2, E[7]*q3)));   \
    float s2_ = fmaf(E[8],q0, fmaf(E[9],q1, fmaf(E[10],q2,E[11]*q3)));  \
    float s3_ = fmaf(E[12],q0,fmaf(E[13],q1,fmaf(E[14],q2,E[15]*q3)));  \
    s0_ = first_ ? e40 : s0_;  s1_ = first_ ? e41 : s1_;                \
    s2_ = first_ ? e42 : s2_;  s3_ = first_ ? e43 : s3_;                \
    const float t0_ = s0_*fe0_, t1_ = s1_*fe1_;                         \
    const float t2_ = s2_*fe2_, t3_ = s3_*fe3_;                         \
    const float cm_ = fmaxf(fmaxf(t0_,t1_), fmaxf(t2_,t3_));            \
    const int ee_ = (int)(__float_as_uint(cm_) >> 23) - 127;            \
    const float n0_ = ldexpf(t0_,-ee_), n1_ = ldexpf(t1_,-ee_);         \
    const float n2_ = ldexpf(t2_,-ee_), n3_ = ldexpf(t3_,-ee_);         \
    q0 = act_ ? n0_ : q0;  q1 = act_ ? n1_ : q1;                        \
    q2 = act_ ? n2_ : q2;  q3 = act_ ? n3_ : q3;                        \
    mex = act_ ? (mex + ee_) : mex;                                     \
    const int tg_ = (TGV);                                              \
    const float fs_ = (tg_ & 2) ? ((tg_ & 1) ? fd_ : fc_)               \
                                : ((tg_ & 1) ? fb2_ : fa_);             \
    gold += act_ ? ((LUTV) + fs_) : 0.0f;                               \
    prev = act_ ? tg_ : prev;                                           \
  } while (0)

#define VPROC(B0,B1,B2,B3,B4,B5,TG,C)                                   \
  do {                                                                  \
    const int r0_ = (C) * 4;                                            \
    const int g0_ = (TG).x & 3, g1_ = (TG).y & 3;                       \
    const int g2_ = (TG).z & 3, g3_ = (TG).w & 3;                       \
    const float u0_ = sT[g0_*6 + prev];                                 \
    const float u1_ = sT[g1_*6 + g0_];                                  \
    const float u2_ = sT[g2_*6 + g1_];                                  \
    const float u3_ = sT[g3_*6 + g2_];                                  \
    VSTEP((B0).x,(B0).y,(B0).z,(B0).w, g0_, u0_, r0_+0);                \
    VSTEP((B1).z,(B1).w,(B2).x,(B2).y, g1_, u1_, r0_+1);                \
    VSTEP((B3).x,(B3).y,(B3).z,(B3).w, g2_, u2_, r0_+2);                \
    VSTEP((B4).z,(B4).w,(B5).x,(B5).y, g3_, u3_, r0_+3);                \
  } while (0)

// ======================= matrix path (segments > 0) =====================
// p[i*4+j]: column j = image of initial state j. Step: P <- diag(fe)*E*P.
#define MSTEP(FA,FB,FC,FD,TGV,LUTV,R)                                   \
  do {                                                                  \
    const bool act_ = (R) < act;                                        \
    const float fa_=(FA), fb2_=(FB), fc_=(FC), fd_=(FD);                \
    const float fe0_=__expf(fa_), fe1_=__expf(fb2_);                    \
    const float fe2_=__expf(fc_), fe3_=__expf(fd_);                     \
    _Pragma("unroll")                                                   \
    for (int j = 0; j < 4; ++j) {                                       \
      const float c0_=p[0+j], c1_=p[4+j], c2_=p[8+j], c3_=p[12+j];      \
      const float t0_=fmaf(E[0],c0_, fmaf(E[1],c1_, fmaf(E[2],c2_, E[3]*c3_)));   \
      const float t1_=fmaf(E[4],c0_, fmaf(E[5],c1_, fmaf(E[6],c2_, E[7]*c3_)));   \
      const float t2_=fmaf(E[8],c0_, fmaf(E[9],c1_, fmaf(E[10],c2_,E[11]*c3_)));  \
      const float t3_=fmaf(E[12],c0_,fmaf(E[13],c1_,fmaf(E[14],c2_,E[15]*c3_)));  \
      p[0+j]  = act_ ? t0_*fe0_ : p[0+j];                               \
      p[4+j]  = act_ ? t1_*fe1_ : p[4+j];                               \
      p[8+j]  = act_ ? t2_*fe2_ : p[8+j];                               \
      p[12+j] = act_ ? t3_*fe3_ : p[12+j];                              \
    }                                                                   \
    const int tg_ = (TGV);                                              \
    const float fs_ = (tg_ & 2) ? ((tg_ & 1) ? fd_ : fc_)               \
                                : ((tg_ & 1) ? fb2_ : fa_);             \
    gold += act_ ? ((LUTV) + fs_) : 0.0f;                               \
    prev = act_ ? tg_ : prev;                                           \
  } while (0)

// Renorm whole matrix by exponent of max entry. Exact (power of 2), so it is
// safe to apply even for lanes already past their active prefix.
#define MRENORM                                                         \
  do {                                                                  \
    float m_ = p[0];                                                    \
    _Pragma("unroll") for (int i = 1; i < 16; ++i) m_ = fmaxf(m_, p[i]);\
    const int ee_ = (int)(__float_as_uint(m_) >> 23) - 127;             \
    _Pragma("unroll") for (int i = 0; i < 16; ++i) p[i]=ldexpf(p[i],-ee_);\
    mex += ee_;                                                         \
  } while (0)

#define MPROC(B0,B1,B2,B3,B4,B5,TG,C)                                   \
  do {                                                                  \
    const int r0_ = (C) * 4;                                            \
    const int g0_ = (TG).x & 3, g1_ = (TG).y & 3;                       \
    const int g2_ = (TG).z & 3, g3_ = (TG).w & 3;                       \
    const float u0_ = sT[g0_*6 + prev];                                 \
    const float u1_ = sT[g1_*6 + g0_];                                  \
    const float u2_ = sT[g2_*6 + g1_];                                  \
    const float u3_ = sT[g3_*6 + g2_];                                  \
    MSTEP((B0).x,(B0).y,(B0).z,(B0).w, g0_, u0_, r0_+0);                \
    MSTEP((B1).z,(B1).w,(B2).x,(B2).y, g1_, u1_, r0_+1);                \
    MSTEP((B3).x,(B3).y,(B3).z,(B3).w, g2_, u2_, r0_+2);                \
    MSTEP((B4).z,(B4).w,(B5).x,(B5).y, g3_, u3_, r0_+3);                \
    MRENORM;                                                            \
  } while (0)

template<int S>
__global__ __launch_bounds__(64) void crf_seg(
    const float* __restrict__ feats,
    const float* __restrict__ trans,
    const int*   __restrict__ tags,
    const int*   __restrict__ lens,
    float* __restrict__ mats,   // [S][16][B]
    int*   __restrict__ mexs,   // [S][B]
    float* __restrict__ golds)  // [S][B]
{
    constexpr int LSEG = LL / S;
    constexpr int NCH  = LSEG / 4;

    __shared__ float sT[36];   // raw transitions (gold LUT, terminal row)
    __shared__ float sE[16];   // exp(trans[i][j]), i,j in 0..3
    __shared__ float sE4[4];   // exp(trans[i][START])

    const int tid = threadIdx.x;
    if (tid < 36) sT[tid] = trans[tid];
    if (tid < 16) sE[tid] = __expf(trans[(tid >> 2) * 6 + (tid & 3)]);
    if (tid < 4)  sE4[tid] = __expf(trans[tid * 6 + 4]);
    __syncthreads();

    const int s    = blockIdx.x % S;          // uniform within block
    const int bgrp = blockIdx.x / S;
    const int b    = bgrp * 64 + tid;
    const int len  = lens[b];
    const int s0   = s * LSEG;
    const int act  = min(len - s0, LSEG);     // active steps (may be <= 0)
    const float* fb = feats + (size_t)b * (LL*6) + (size_t)s0 * 6;
    const int*   tb = tags  + (size_t)b * LL + s0;

    float E[16];
    #pragma unroll
    for (int i = 0; i < 16; ++i) E[i] = sE[i];

    float gold = 0.f;
    int   mex  = 0;
    int   prev = (s == 0) ? 4 : (tb[-1] & 3);   // START or boundary tag

    const float4 z4 = make_float4(0.f,0.f,0.f,0.f);
    const int4   zi = make_int4(0,0,0,0);
    float4 a0=z4,a1=z4,a2=z4,a3=z4,a4=z4,a5=z4;
    float4 b0=z4,b1=z4,b2=z4,b3=z4,b4=z4,b5=z4;
    int4 at=zi, bt=zi;

    const int nch = (max(act, 0) + 3) >> 2;

    if (s == 0) {
        // ---- vector path ----
        const float e40=sE4[0], e41=sE4[1], e42=sE4[2], e43=sE4[3];
        float q0=0.f, q1=0.f, q2=0.f, q3=0.f;
        LOADC(a0,a1,a2,a3,a4,a5,at, 0);
        for (int c = 0; c < nch; c += 2) {
            LOADC(b0,b1,b2,b3,b4,b5,bt, c+1);
            VPROC(a0,a1,a2,a3,a4,a5,at, c);
            if (c + 1 >= nch) break;
            LOADC(a0,a1,a2,a3,a4,a5,at, c+2);
            VPROC(b0,b1,b2,b3,b4,b5,bt, c+1);
        }
        mats[(size_t)0*BB + b] = q0;
        mats[(size_t)1*BB + b] = q1;
        mats[(size_t)2*BB + b] = q2;
        mats[(size_t)3*BB + b] = q3;
    } else {
        // ---- matrix path ----
        float p[16];
        #pragma unroll
        for (int i = 0; i < 16; ++i) p[i] = (i % 5 == 0) ? 1.f : 0.f;
        LOADC(a0,a1,a2,a3,a4,a5,at, 0);
        for (int c = 0; c < nch; c += 2) {
            LOADC(b0,b1,b2,b3,b4,b5,bt, c+1);
            MPROC(a0,a1,a2,a3,a4,a5,at, c);
            if (c + 1 >= nch) break;
            LOADC(a0,a1,a2,a3,a4,a5,at, c+2);
            MPROC(b0,b1,b2,b3,b4,b5,bt, c+1);
        }
        #pragma unroll
        for (int t = 0; t < 16; ++t)
            mats[((size_t)s*16 + t)*BB + b] = p[t];
    }

    // terminal gold: this segment owns step len-1  <=>  len in (s0, s0+LSEG]
    if (len > s0 && len <= s0 + LSEG)
        gold += sT[30 + (tb[len - 1 - s0] & 3)];

    mexs [(size_t)s*BB + b] = mex;
    golds[(size_t)s*BB + b] = gold;
}

template<int S>
__global__ __launch_bounds__(64) void crf_comb(
    const float* __restrict__ mats,
    const int*   __restrict__ mexs,
    const float* __restrict__ golds,
    const float* __restrict__ trans,
    const int*   __restrict__ lens,
    float* __restrict__ out)
{
    constexpr int LSEG = LL / S;
    const int tid = threadIdx.x;
    const int b   = blockIdx.x * 64 + tid;
    const int len = lens[b];

    float v[4];
    #pragma unroll
    for (int i = 0; i < 4; ++i) v[i] = mats[(size_t)i*BB + b];
    int   mex  = mexs[b];
    float gold = golds[b];

    float cur[16], nxt[16];
    if (S > 1 && LSEG < len) {
        #pragma unroll
        for (int t = 0; t < 16; ++t) nxt[t] = mats[(size_t)(16 + t)*BB + b];
    }
    for (int s = 1; s < S; ++s) {
        if (s * LSEG >= len) break;
        #pragma unroll
        for (int t = 0; t < 16; ++t) cur[t] = nxt[t];
        if (s + 1 < S && (s + 1) * LSEG < len) {
            #pragma unroll
            for (int t = 0; t < 16; ++t)
                nxt[t] = mats[((size_t)(s+1)*16 + t)*BB + b];
        }
        float nv[4];
        #pragma unroll
        for (int i = 0; i < 4; ++i)
            nv[i] = fmaf(cur[i*4+0],v[0], fmaf(cur[i*4+1],v[1],
                    fmaf(cur[i*4+2],v[2], cur[i*4+3]*v[3])));
        const float m_ = fmaxf(fmaxf(nv[0],nv[1]), fmaxf(nv[2],nv[3]));
        const int ee = (int)(__float_as_uint(m_) >> 23) - 127;
        #pragma unroll
        for (int i = 0; i < 4; ++i) v[i] = ldexpf(nv[i], -ee);
        mex  += ee + mexs[(size_t)s*BB + b];
        gold += golds[(size_t)s*BB + b];
    }

    const float e50=__expf(trans[30]), e51=__expf(trans[31]);
    const float e52=__expf(trans[32]), e53=__expf(trans[33]);
    const float dot = fmaf(e50,v[0], fmaf(e51,v[1], fmaf(e52,v[2], e53*v[3])));
    const float logz = fmaf((float)mex, LN2F, __logf(dot));
    float r = logz - gold;

    #pragma unroll
    for (int off = 32; off > 0; off >>= 1)
        r += __shfl_xor(r, off, 64);
    if (tid == 0)
        atomicAdd(out, r * (1.0f / 8192.0f));
}

extern "C" void kernel_launch(void* const* d_in, const int* in_sizes, int n_in,
                              void* d_out, int out_size, void* d_ws, size_t ws_size,
                              hipStream_t stream) {
    const float* feats = (const float*)d_in[0];
    const float* trans = (const float*)d_in[1];
    const int*   tags  = (const int*)d_in[2];
    const int*   lens  = (const int*)d_in[3];
    float* out = (float*)d_out;

    // workspace: mats [S][16][B] f32, mexs [S][B] i32, golds [S][B] f32
    int S = 16;
    while (S > 1 && (size_t)S * BB * (16 + 2) * 4 > ws_size) S >>= 1;

    float* mats  = (float*)d_ws;
    int*   mexs  = (int*)  (mats + (size_t)S * 16 * BB);
    float* golds = (float*)(mexs + (size_t)S * BB);

    hipMemsetAsync(out, 0, sizeof(float) * out_size, stream);

    switch (S) {
      case 16:
        crf_seg<16><<<128*16, 64, 0, stream>>>(feats, trans, tags, lens, mats, mexs, golds);
        crf_comb<16><<<128, 64, 0, stream>>>(mats, mexs, golds, trans, lens, out);
        break;
      case 8:
        crf_seg<8><<<128*8, 64, 0, stream>>>(feats, trans, tags, lens, mats, mexs, golds);
        crf_comb<8><<<128, 64, 0, stream>>>(mats, mexs, golds, trans, lens, out);
        break;
      case 4:
        crf_seg<4><<<128*4, 64, 0, stream>>>(feats, trans, tags, lens, mats, mexs, golds);
        crf_comb<4><<<128, 64, 0, stream>>>(mats, mexs, golds, trans, lens, out);
        break;
      case 2:
        crf_seg<2><<<128*2, 64, 0, stream>>>(feats, trans, tags, lens, mats, mexs, golds);
        crf_comb<2><<<128, 64, 0, stream>>>(mats, mexs, golds, trans, lens, out);
        break;
      default:
        crf_seg<1><<<128, 64, 0, stream>>>(feats, trans, tags, lens, mats, mexs, golds);
        crf_comb<1><<<128, 64, 0, stream>>>(mats, mexs, golds, trans, lens, out);
        break;
    }
}